// Round 11
// baseline (112.066 us; speedup 1.0000x reference)
//
#include <hip/hip_runtime.h>
#include <hip/hip_fp16.h>

// SimpleMHA2D: B=32, S=HW=1024, C=KV=1024, N=16, K=V=64, fp32.
//  K1: qk2[nh*8192 + nq2*4096 + c*4 + (n&3)],  nh=n>>3, nq2=(n>>2)&1
//  K2 (fused, per (b, 64-row chunk, 8-head half)): logits (LDS qkt 32KB)
//      -> chunk softmax -> wp[blk][nl][c] (fp16).  Deferred rescale in K3.
//  K3: out[b][n][v] = (sum_ch fac*wp . vk)/(sum_ch fac*l_ch) + vb.

__device__ __forceinline__ float rlane(float v, int l) {
  return __int_as_float(__builtin_amdgcn_readlane(__float_as_int(v), l));
}

// ---------------- K1: fold query into k_kernel (emit split-qkt layout) ----------------
__global__ __launch_bounds__(256) void k_qk(const float* __restrict__ kk,
                                            const float* __restrict__ q,
                                            const float* __restrict__ kb,
                                            float* __restrict__ qk2,
                                            float* __restrict__ qb) {
  const int gid = blockIdx.x * 256 + threadIdx.x;   // 16384 = 1024c * 16n
  const int c = gid >> 4, n = gid & 15;
  float a = 0.f;
#pragma unroll
  for (int k4 = 0; k4 < 64; k4 += 4) {
    const float4 kv = *(const float4*)(kk + (size_t)c * 1024 + n * 64 + k4);
    const float4 qv = *(const float4*)(q + n * 64 + k4);
    a += kv.x * qv.x + kv.y * qv.y + kv.z * qv.z + kv.w * qv.w;
  }
  qk2[(n >> 3) * 8192 + ((n >> 2) & 1) * 4096 + c * 4 + (n & 3)] = a;
  if (blockIdx.x == 0 && threadIdx.x < 16) {
    float s = 0.f;
    for (int k = 0; k < 64; k++) s += kb[threadIdx.x * 64 + k] * q[threadIdx.x * 64 + k];
    qb[threadIdx.x] = s;
  }
}

// ---------------- K2: fused logits + chunk softmax + weighted sum ----------------
// 1024 blocks = (b*16+ch)*2 + nh; 512 thr (8 waves). 8 heads per block.
// LDS: qkt[2 nq2][1024 c][4] fp32 = 32 KB (read-only after staging)
//      + et2[64 rows][9] = 2.3 KB  ->  ~34.3 KB -> 4 blocks/CU, 8 waves/SIMD.
__global__ __launch_bounds__(512, 8) void k_fused(const float* __restrict__ x,
                                                  const float* __restrict__ qk2,
                                                  const float* __restrict__ qb,
                                                  float* __restrict__ mch,
                                                  float* __restrict__ lch,
                                                  __half* __restrict__ wph) {
  __shared__ float qkt[8192];
  __shared__ float et2[64 * 9 + 4];
  const int tid = threadIdx.x;
  const int lane = tid & 63;
  const int wid = tid >> 6;          // 0..7
  const int blk = blockIdx.x;        // (b*16+ch)*2 + nh
  const int nh = blk & 1;
  const int srow0 = (blk >> 1) * 64; // global row base

  // stage qk2 half -> qkt (identity copy)
  {
    const float* qsrc = qk2 + (size_t)nh * 8192;
#pragma unroll
    for (int it = 0; it < 4; ++it) {
      const int g = it * 512 + tid;  // quad 0..2047
      *(float4*)&qkt[g * 4] = *(const float4*)(qsrc + (size_t)g * 4);
    }
  }
  __syncthreads();

  // ---- Phase A: logits for 64 rows x 8 heads (2 sweeps x 8 waves x 4 rows) ----
#pragma unroll 1
  for (int sweep = 0; sweep < 2; ++sweep) {
    const int rloc = sweep * 32 + wid * 4;
    const float* xw = x + (size_t)(srow0 + rloc) * 1024 + lane;

    float acc[4][8];
#pragma unroll
    for (int r = 0; r < 4; ++r)
#pragma unroll
      for (int n = 0; n < 8; ++n) acc[r][n] = 0.f;

    float xa[4], xb[4];
#pragma unroll
    for (int r = 0; r < 4; ++r) xa[r] = xw[(size_t)r * 1024];

#pragma unroll 1
    for (int st = 0; st < 16; st += 2) {
#pragma unroll
      for (int r = 0; r < 4; ++r) xb[r] = xw[(size_t)r * 1024 + (st + 1) * 64];
      {
        const int c4 = (st * 64 + lane) * 4;
#pragma unroll
        for (int nq = 0; nq < 2; ++nq) {
          const float4 qv = *(const float4*)&qkt[nq * 4096 + c4];
#pragma unroll
          for (int r = 0; r < 4; ++r) {
            acc[r][nq * 4 + 0] += xa[r] * qv.x;
            acc[r][nq * 4 + 1] += xa[r] * qv.y;
            acc[r][nq * 4 + 2] += xa[r] * qv.z;
            acc[r][nq * 4 + 3] += xa[r] * qv.w;
          }
        }
      }
      if (st + 2 < 16) {
#pragma unroll
        for (int r = 0; r < 4; ++r) xa[r] = xw[(size_t)r * 1024 + (st + 2) * 64];
      }
      {
        const int c4 = ((st + 1) * 64 + lane) * 4;
#pragma unroll
        for (int nq = 0; nq < 2; ++nq) {
          const float4 qv = *(const float4*)&qkt[nq * 4096 + c4];
#pragma unroll
          for (int r = 0; r < 4; ++r) {
            acc[r][nq * 4 + 0] += xb[r] * qv.x;
            acc[r][nq * 4 + 1] += xb[r] * qv.y;
            acc[r][nq * 4 + 2] += xb[r] * qv.z;
            acc[r][nq * 4 + 3] += xb[r] * qv.w;
          }
        }
      }
    }

    // reduce-scatter butterfly: fold bits 0..2 (distribute 8 n), sum bits 3..5
    const int b0 = lane & 1, b1 = (lane >> 1) & 1, b2 = (lane >> 2) & 1;
    float f[4];
#pragma unroll
    for (int r = 0; r < 4; ++r) {
      float u[4];
#pragma unroll
      for (int m = 0; m < 4; ++m) {
        const float keep = b0 ? acc[r][2 * m + 1] : acc[r][2 * m];
        const float give = b0 ? acc[r][2 * m]     : acc[r][2 * m + 1];
        u[m] = keep + __shfl_xor(give, 1);
      }
      float w[2];
#pragma unroll
      for (int p = 0; p < 2; ++p) {
        const float keep = b1 ? u[2 * p + 1] : u[2 * p];
        const float give = b1 ? u[2 * p]     : u[2 * p + 1];
        w[p] = keep + __shfl_xor(give, 2);
      }
      {
        const float keep = b2 ? w[1] : w[0];
        const float give = b2 ? w[0] : w[1];
        float t = keep + __shfl_xor(give, 4);
        t += __shfl_xor(t, 8);
        t += __shfl_xor(t, 16);
        t += __shfl_xor(t, 32);
        f[r] = t;
      }
    }
    const int rsel = (lane >> 3) & 3;
    float val = (rsel == 0) ? f[0] : (rsel == 1) ? f[1] : (rsel == 2) ? f[2] : f[3];
    val += qb[nh * 8 + (lane & 7)];
    if (lane < 32) et2[(rloc + rsel) * 9 + (lane & 7)] = val;   // et2[row][nl]
  }
  __syncthreads();

  // ---- Phase B: chunk softmax; wave wid <-> head nl=wid, lane <-> row ----
  {
    const float v = et2[lane * 9 + wid];
    float m = v;
#pragma unroll
    for (int d = 1; d < 64; d <<= 1) m = fmaxf(m, __shfl_xor(m, d));
    const float e = __expf(v - m);
    float s = e;
#pragma unroll
    for (int d = 1; d < 64; d <<= 1) s += __shfl_xor(s, d);
    if (lane == 0) {
      mch[blk * 8 + wid] = m;
      lch[blk * 8 + wid] = s;
    }
    et2[lane * 9 + wid] = e;   // in-place, same thread -> no race
  }
  __syncthreads();

  // ---- Phase C: wp[blk][nl][c] = sum_s e[s][nl]*x[s][c], c = {2*tid, 2*tid+1} ----
  {
    const int c0 = tid * 2;
    float acc0[8], acc1[8];
#pragma unroll
    for (int n = 0; n < 8; ++n) { acc0[n] = 0.f; acc1[n] = 0.f; }
    const float* xp = x + (size_t)srow0 * 1024 + c0;

    // rolling distance-1 pipeline, named buffers
    float  ea = et2[((lane >> 3) & 3) * 9 + (lane & 7)];
    float2 xca[4];
#pragma unroll
    for (int ss = 0; ss < 4; ++ss) xca[ss] = *(const float2*)(xp + (size_t)ss * 1024);

#pragma unroll 1
    for (int sg = 0; sg < 16; ++sg) {
      float  eb = 0.f;
      float2 xcb[4];
      if (sg < 15) {
        const int s0n = (sg + 1) * 4;
        eb = et2[(s0n + ((lane >> 3) & 3)) * 9 + (lane & 7)];
#pragma unroll
        for (int ss = 0; ss < 4; ++ss)
          xcb[ss] = *(const float2*)(xp + (size_t)(s0n + ss) * 1024);
      }
#pragma unroll
      for (int ss = 0; ss < 4; ++ss) {
#pragma unroll
        for (int n = 0; n < 8; ++n) {
          const float ev = rlane(ea, ss * 8 + n);  // lane ss*8+n holds e[sg*4+ss][n]
          acc0[n] += ev * xca[ss].x;
          acc1[n] += ev * xca[ss].y;
        }
      }
      ea = eb;
#pragma unroll
      for (int ss = 0; ss < 4; ++ss) xca[ss] = xcb[ss];
    }

    __half* wpp = wph + (size_t)blk * 8192;
#pragma unroll
    for (int n = 0; n < 8; ++n) {
      __half2 h = __floats2half2_rn(acc0[n], acc1[n]);
      *(__half2*)(wpp + n * 1024 + c0) = h;
    }
  }
}

// ---------------- K3: out = (sum_ch fac*wp . vk)/lg + vb ----------------
__global__ __launch_bounds__(256) void k_out(const __half* __restrict__ wph,
                                             const float* __restrict__ vk,
                                             const float* __restrict__ vb,
                                             const float* __restrict__ mch,
                                             const float* __restrict__ lch,
                                             float* __restrict__ out) {
  const int bi = blockIdx.x;  // b*16+n, 512 blocks
  const int b = bi >> 4, n = bi & 15;
  const int nh = n >> 3, nl = n & 7;
  const int tid = threadIdx.x;
  __shared__ float wrow[1024];
  __shared__ float red[4][64];

  float m16[16], l16[16];
#pragma unroll
  for (int ch = 0; ch < 16; ++ch) {
    const int cblk = ((b * 16 + ch) * 2 + nh);
    m16[ch] = mch[cblk * 8 + nl];
    l16[ch] = lch[cblk * 8 + nl];
  }
  float mg = m16[0];
#pragma unroll
  for (int ch = 1; ch < 16; ++ch) mg = fmaxf(mg, m16[ch]);
  float fac[16], lg = 0.f;
#pragma unroll
  for (int ch = 0; ch < 16; ++ch) { fac[ch] = __expf(m16[ch] - mg); lg += fac[ch] * l16[ch]; }

  float4 a4 = {0.f, 0.f, 0.f, 0.f};
#pragma unroll
  for (int ch = 0; ch < 16; ch++) {
    const int cblk = ((b * 16 + ch) * 2 + nh);
    const __half2* p = (const __half2*)(wph + ((size_t)cblk * 8 + nl) * 1024 + tid * 4);
    const float2 f01 = __half22float2(p[0]);
    const float2 f23 = __half22float2(p[1]);
    a4.x += fac[ch] * f01.x; a4.y += fac[ch] * f01.y;
    a4.z += fac[ch] * f23.x; a4.w += fac[ch] * f23.y;
  }
  *(float4*)&wrow[tid * 4] = a4;
  __syncthreads();

  const int v = tid & 63, cq = tid >> 6;
  float a = 0.f;
  const float* vkc = vk + n * 64 + v;
  for (int ci = 0; ci < 256; ci++) {
    const int c = cq * 256 + ci;
    a += wrow[c] * vkc[(size_t)c * 1024];
  }
  red[cq][v] = a;
  __syncthreads();
  if (tid < 64) {
    const float o = (red[0][tid] + red[1][tid] + red[2][tid] + red[3][tid]) / lg
                    + vb[n * 64 + tid];
    out[(size_t)b * 1024 + n * 64 + tid] = o;
  }
}

extern "C" void kernel_launch(void* const* d_in, const int* in_sizes, int n_in,
                              void* d_out, int out_size, void* d_ws, size_t ws_size,
                              hipStream_t stream) {
  const float* x  = (const float*)d_in[0];  // key_value [32,32,32,1024]
  const float* q  = (const float*)d_in[1];  // query [1,1,16,64]
  const float* kk = (const float*)d_in[2];  // k_kernel [1024,1024]
  const float* kb = (const float*)d_in[3];  // k_bias [1024]
  const float* vk = (const float*)d_in[4];  // v_kernel [1024,1024]
  const float* vb = (const float*)d_in[5];  // v_bias [1024]
  float* out = (float*)d_out;               // [32,16,64] fp32

  float*  f   = (float*)d_ws;
  float*  qk2 = f;             // 16384 (split-qkt layout)
  float*  qb  = f + 16384;     // 16
  float*  mch = f + 16400;     // 8192  [1024 blk][8 nl]
  float*  lch = f + 24592;     // 8192
  __half* wph = (__half*)(f + 32784);  // 1024 blk * 8 nl * 1024 c = 16 MB

  hipLaunchKernelGGL(k_qk,    dim3(64),   dim3(256), 0, stream, kk, q, kb, qk2, qb);
  hipLaunchKernelGGL(k_fused, dim3(1024), dim3(512), 0, stream, x, qk2, qb, mch, lch, wph);
  hipLaunchKernelGGL(k_out,   dim3(512),  dim3(256), 0, stream, wph, vk, vb, mch, lch, out);
}

// Round 12
// 69.252 us; speedup vs baseline: 1.6182x; 1.6182x over previous
//
#include <hip/hip_runtime.h>
#include <hip/hip_fp16.h>

// SimpleMHA2D: B=32, S=HW=1024, C=KV=1024, N=16, K=V=64, fp32.
//  K1: qkh[nq*4096 + c*4 + (n&3)] (fp16) = sum_k kk[c][n*64+k]*q[n][k]
//  K2 (fused, per 64-row chunk): logits (LDS qkt fp16, 32KB) -> chunk softmax
//      -> wp[blk][n][c] (fp16) via readlane-broadcast e.  Deferred rescale.
//  K3: out[b][n][v] = (sum_ch fac*wp . vk)/(sum_ch fac*l_ch) + vb.

__device__ __forceinline__ float rlane(float v, int l) {
  return __int_as_float(__builtin_amdgcn_readlane(__float_as_int(v), l));
}

// ---------------- K1: fold query into k_kernel (emit fp16 qkt layout) ----------------
__global__ __launch_bounds__(256) void k_qk(const float* __restrict__ kk,
                                            const float* __restrict__ q,
                                            const float* __restrict__ kb,
                                            __half* __restrict__ qkh,
                                            float* __restrict__ qb) {
  const int gid = blockIdx.x * 256 + threadIdx.x;   // 16384 = 1024c * 16n
  const int c = gid >> 4, n = gid & 15;
  float a = 0.f;
#pragma unroll
  for (int k4 = 0; k4 < 64; k4 += 4) {
    const float4 kv = *(const float4*)(kk + (size_t)c * 1024 + n * 64 + k4);
    const float4 qv = *(const float4*)(q + n * 64 + k4);
    a += kv.x * qv.x + kv.y * qv.y + kv.z * qv.z + kv.w * qv.w;
  }
  qkh[(n >> 2) * 4096 + c * 4 + (n & 3)] = __float2half(a);
  if (blockIdx.x == 0 && threadIdx.x < 16) {
    float s = 0.f;
    for (int k = 0; k < 64; k++) s += kb[threadIdx.x * 64 + k] * q[threadIdx.x * 64 + k];
    qb[threadIdx.x] = s;
  }
}

// ---------------- K2: fused logits + chunk softmax + weighted sum ----------------
// 512 blocks (32 b x 16 chunks of 64 rows), 512 thr (8 waves).
// LDS: qkt fp16 [nq][c][4] = 32 KB (read-only after staging) + et2 4.3 KB
//  -> ~37 KB -> 4 blocks/CU = 8 waves/SIMD (2x R10's latency hiding).
__global__ __launch_bounds__(512, 4) void k_fused(const float* __restrict__ x,
                                                  const __half* __restrict__ qkh,
                                                  const float* __restrict__ qb,
                                                  float* __restrict__ mch,
                                                  float* __restrict__ lch,
                                                  __half* __restrict__ wph) {
  __shared__ uint2 qkt[4096];      // [nq][1024 c], 4 halves each
  __shared__ float et2[64 * 17 + 4];
  const int tid = threadIdx.x;
  const int lane = tid & 63;
  const int wid = tid >> 6;          // 0..7
  const int blk = blockIdx.x;        // b*16 + ch
  const int srow0 = blk * 64;        // global row base

  // stage qkh -> qkt (identity copy, 32 KB)
  {
    const uint4* src = (const uint4*)qkh;  // 2048 uint4
#pragma unroll
    for (int it = 0; it < 4; ++it) {
      const int g = it * 512 + tid;
      ((uint4*)qkt)[g] = src[g];
    }
  }
  __syncthreads();

  // ---- Phase A: logits for 64 rows (2 sweeps x 8 waves x 4 rows) ----
#pragma unroll 1
  for (int sweep = 0; sweep < 2; ++sweep) {
    const int rloc = sweep * 32 + wid * 4;
    const float* xw = x + (size_t)(srow0 + rloc) * 1024 + lane;

    float acc[4][16];
#pragma unroll
    for (int r = 0; r < 4; ++r)
#pragma unroll
      for (int n = 0; n < 16; ++n) acc[r][n] = 0.f;

    float xa[4], xb[4];
#pragma unroll
    for (int r = 0; r < 4; ++r) xa[r] = xw[(size_t)r * 1024];

#pragma unroll 1
    for (int st = 0; st < 16; st += 2) {
#pragma unroll
      for (int r = 0; r < 4; ++r) xb[r] = xw[(size_t)r * 1024 + (st + 1) * 64];
      {
        const int c = st * 64 + lane;
#pragma unroll
        for (int nq = 0; nq < 4; ++nq) {
          const uint2 hv = qkt[nq * 1024 + c];
          const float2 f01 = __half22float2(*(const __half2*)&hv.x);
          const float2 f23 = __half22float2(*(const __half2*)&hv.y);
#pragma unroll
          for (int r = 0; r < 4; ++r) {
            acc[r][nq * 4 + 0] += xa[r] * f01.x;
            acc[r][nq * 4 + 1] += xa[r] * f01.y;
            acc[r][nq * 4 + 2] += xa[r] * f23.x;
            acc[r][nq * 4 + 3] += xa[r] * f23.y;
          }
        }
      }
      if (st + 2 < 16) {
#pragma unroll
        for (int r = 0; r < 4; ++r) xa[r] = xw[(size_t)r * 1024 + (st + 2) * 64];
      }
      {
        const int c = (st + 1) * 64 + lane;
#pragma unroll
        for (int nq = 0; nq < 4; ++nq) {
          const uint2 hv = qkt[nq * 1024 + c];
          const float2 f01 = __half22float2(*(const __half2*)&hv.x);
          const float2 f23 = __half22float2(*(const __half2*)&hv.y);
#pragma unroll
          for (int r = 0; r < 4; ++r) {
            acc[r][nq * 4 + 0] += xb[r] * f01.x;
            acc[r][nq * 4 + 1] += xb[r] * f01.y;
            acc[r][nq * 4 + 2] += xb[r] * f23.x;
            acc[r][nq * 4 + 3] += xb[r] * f23.y;
          }
        }
      }
    }

    // register-only reduce-scatter butterfly (validated R5/R7/R10)
    const int b0 = lane & 1, b1 = (lane >> 1) & 1;
    const int b2 = (lane >> 2) & 1, b3 = (lane >> 3) & 1;
    float f[4];
#pragma unroll
    for (int r = 0; r < 4; ++r) {
      float u[8];
#pragma unroll
      for (int m = 0; m < 8; ++m) {
        const float keep = b0 ? acc[r][2 * m + 1] : acc[r][2 * m];
        const float give = b0 ? acc[r][2 * m]     : acc[r][2 * m + 1];
        u[m] = keep + __shfl_xor(give, 1);
      }
      float w[4];
#pragma unroll
      for (int p = 0; p < 4; ++p) {
        const float keep = b1 ? u[2 * p + 1] : u[2 * p];
        const float give = b1 ? u[2 * p]     : u[2 * p + 1];
        w[p] = keep + __shfl_xor(give, 2);
      }
      float z[2];
#pragma unroll
      for (int qq = 0; qq < 2; ++qq) {
        const float keep = b2 ? w[2 * qq + 1] : w[2 * qq];
        const float give = b2 ? w[2 * qq]     : w[2 * qq + 1];
        z[qq] = keep + __shfl_xor(give, 4);
      }
      {
        const float keep = b3 ? z[1] : z[0];
        const float give = b3 ? z[0] : z[1];
        float t = keep + __shfl_xor(give, 8);
        t += __shfl_xor(t, 16);
        t += __shfl_xor(t, 32);
        f[r] = t;
      }
    }
    const int rsel = lane >> 4;
    float val = (rsel == 0) ? f[0] : (rsel == 1) ? f[1] : (rsel == 2) ? f[2] : f[3];
    val += qb[lane & 15];
    et2[(rloc + rsel) * 17 + (lane & 15)] = val;   // et2[row][n]
  }
  __syncthreads();

  // ---- Phase B: chunk softmax per n (wave handles n = wid, wid+8) ----
#pragma unroll
  for (int t = 0; t < 2; ++t) {
    const int nn = wid + t * 8;
    const float v = et2[lane * 17 + nn];
    float m = v;
#pragma unroll
    for (int d = 1; d < 64; d <<= 1) m = fmaxf(m, __shfl_xor(m, d));
    const float e = __expf(v - m);
    float s = e;
#pragma unroll
    for (int d = 1; d < 64; d <<= 1) s += __shfl_xor(s, d);
    if (lane == 0) {
      mch[blk * 16 + nn] = m;
      lch[blk * 16 + nn] = s;
    }
    et2[lane * 17 + nn] = e;   // in-place, same thread -> no race
  }
  __syncthreads();

  // ---- Phase C: wp[blk][n][c] = sum_s e[s][n]*x[s][c], c = {2*tid, 2*tid+1} ----
  {
    const int c0 = tid * 2;
    float acc0[16], acc1[16];
#pragma unroll
    for (int n = 0; n < 16; ++n) { acc0[n] = 0.f; acc1[n] = 0.f; }
    const float* xp = x + (size_t)srow0 * 1024 + c0;

    // rolling distance-1 pipeline with named buffers (R7/R10 discipline)
    float  ea = et2[(lane >> 4) * 17 + (lane & 15)];
    float2 xca[4];
#pragma unroll
    for (int ss = 0; ss < 4; ++ss) xca[ss] = *(const float2*)(xp + (size_t)ss * 1024);

#pragma unroll 1
    for (int sg = 0; sg < 16; ++sg) {
      float  eb = 0.f;
      float2 xcb[4];
      if (sg < 15) {
        const int s0n = (sg + 1) * 4;
        eb = et2[(s0n + (lane >> 4)) * 17 + (lane & 15)];
#pragma unroll
        for (int ss = 0; ss < 4; ++ss)
          xcb[ss] = *(const float2*)(xp + (size_t)(s0n + ss) * 1024);
      }
#pragma unroll
      for (int ss = 0; ss < 4; ++ss) {
#pragma unroll
        for (int n = 0; n < 16; ++n) {
          const float ev = rlane(ea, ss * 16 + n);  // lane ss*16+n holds e[sg*4+ss][n]
          acc0[n] += ev * xca[ss].x;
          acc1[n] += ev * xca[ss].y;
        }
      }
      ea = eb;
#pragma unroll
      for (int ss = 0; ss < 4; ++ss) xca[ss] = xcb[ss];
    }

    __half* wpp = wph + (size_t)blk * 16384;
#pragma unroll
    for (int n = 0; n < 16; ++n) {
      __half2 h = __floats2half2_rn(acc0[n], acc1[n]);
      *(__half2*)(wpp + n * 1024 + c0) = h;
    }
  }
}

// ---------------- K3: out = (sum_ch fac*wp . vk)/lg + vb ----------------
__global__ __launch_bounds__(256) void k_out(const __half* __restrict__ wph,
                                             const float* __restrict__ vk,
                                             const float* __restrict__ vb,
                                             const float* __restrict__ mch,
                                             const float* __restrict__ lch,
                                             float* __restrict__ out) {
  const int bi = blockIdx.x;  // b*16+n, 512 blocks
  const int b = bi >> 4, n = bi & 15;
  const int tid = threadIdx.x;
  __shared__ float wrow[1024];
  __shared__ float red[4][64];

  float m16[16], l16[16];
#pragma unroll
  for (int ch = 0; ch < 16; ++ch) {
    m16[ch] = mch[(b * 16 + ch) * 16 + n];
    l16[ch] = lch[(b * 16 + ch) * 16 + n];
  }
  float mg = m16[0];
#pragma unroll
  for (int ch = 1; ch < 16; ++ch) mg = fmaxf(mg, m16[ch]);
  float fac[16], lg = 0.f;
#pragma unroll
  for (int ch = 0; ch < 16; ++ch) { fac[ch] = __expf(m16[ch] - mg); lg += fac[ch] * l16[ch]; }

  float4 a4 = {0.f, 0.f, 0.f, 0.f};
#pragma unroll
  for (int ch = 0; ch < 16; ch++) {
    const __half2* p = (const __half2*)(wph + ((size_t)(b * 16 + ch) * 16 + n) * 1024 + tid * 4);
    const float2 f01 = __half22float2(p[0]);
    const float2 f23 = __half22float2(p[1]);
    a4.x += fac[ch] * f01.x; a4.y += fac[ch] * f01.y;
    a4.z += fac[ch] * f23.x; a4.w += fac[ch] * f23.y;
  }
  *(float4*)&wrow[tid * 4] = a4;
  __syncthreads();

  const int v = tid & 63, cq = tid >> 6;
  float a = 0.f;
  const float* vkc = vk + n * 64 + v;
  for (int ci = 0; ci < 256; ci++) {
    const int c = cq * 256 + ci;
    a += wrow[c] * vkc[(size_t)c * 1024];
  }
  red[cq][v] = a;
  __syncthreads();
  if (tid < 64) {
    const float o = (red[0][tid] + red[1][tid] + red[2][tid] + red[3][tid]) / lg
                    + vb[n * 64 + tid];
    out[(size_t)b * 1024 + n * 64 + tid] = o;
  }
}

extern "C" void kernel_launch(void* const* d_in, const int* in_sizes, int n_in,
                              void* d_out, int out_size, void* d_ws, size_t ws_size,
                              hipStream_t stream) {
  const float* x  = (const float*)d_in[0];  // key_value [32,32,32,1024]
  const float* q  = (const float*)d_in[1];  // query [1,1,16,64]
  const float* kk = (const float*)d_in[2];  // k_kernel [1024,1024]
  const float* kb = (const float*)d_in[3];  // k_bias [1024]
  const float* vk = (const float*)d_in[4];  // v_kernel [1024,1024]
  const float* vb = (const float*)d_in[5];  // v_bias [1024]
  float* out = (float*)d_out;               // [32,16,64] fp32

  float*  f   = (float*)d_ws;
  __half* qkh = (__half*)f;            // 16384 halves = 32 KB (qkt layout)
  float*  qb  = f + 8192;              // 16
  float*  mch = f + 8208;              // 8192  [512 blk][16 n]
  float*  lch = f + 16400;             // 8192
  __half* wph = (__half*)(f + 24592);  // 8388608 halves = 16 MB

  hipLaunchKernelGGL(k_qk,    dim3(64),  dim3(256), 0, stream, kk, q, kb, qkh, qb);
  hipLaunchKernelGGL(k_fused, dim3(512), dim3(512), 0, stream, x, qkh, qb, mch, lch, wph);
  hipLaunchKernelGGL(k_out,   dim3(512), dim3(256), 0, stream, wph, vk, vb, mch, lch, out);
}

// Round 13
// 66.981 us; speedup vs baseline: 1.6731x; 1.0339x over previous
//
#include <hip/hip_runtime.h>
#include <hip/hip_fp16.h>

// SimpleMHA2D: B=32, S=HW=1024, C=KV=1024, N=16, K=V=64, fp32.
//  K1: qkb B-fragments (fp16): qkb[kb][lane][j] = qk[c][n],
//      c = kb*32 + (lane>>4)*8 + j, n = lane&15.
//  K2 (fused, per 64-row chunk): phase A = MFMA 16x16x32_f16 logits
//      -> chunk softmax -> phase C (readlane) wp fp16.  Deferred rescale.
//  K3: out[b][n][v] = (sum_ch fac*wp . vk)/(sum_ch fac*l_ch) + vb.

typedef _Float16 f16x8 __attribute__((ext_vector_type(8)));
typedef float f32x4 __attribute__((ext_vector_type(4)));

__device__ __forceinline__ float rlane(float v, int l) {
  return __int_as_float(__builtin_amdgcn_readlane(__float_as_int(v), l));
}

// ---------------- K1: fold query into k_kernel (emit B-fragment layout) ----------------
__global__ __launch_bounds__(256) void k_qk(const float* __restrict__ kk,
                                            const float* __restrict__ q,
                                            const float* __restrict__ kb,
                                            __half* __restrict__ qkb,
                                            float* __restrict__ qb) {
  const int gid = blockIdx.x * 256 + threadIdx.x;   // 16384 = 1024c * 16n
  const int c = gid >> 4, n = gid & 15;
  float a = 0.f;
#pragma unroll
  for (int k4 = 0; k4 < 64; k4 += 4) {
    const float4 kv = *(const float4*)(kk + (size_t)c * 1024 + n * 64 + k4);
    const float4 qv = *(const float4*)(q + n * 64 + k4);
    a += kv.x * qv.x + kv.y * qv.y + kv.z * qv.z + kv.w * qv.w;
  }
  // B-fragment position: kb=c>>5, lane=((c>>3)&3)*16+n, j=c&7
  const int kbi = c >> 5;
  const int l = (((c >> 3) & 3) << 4) | n;
  const int j = c & 7;
  qkb[kbi * 512 + l * 8 + j] = __float2half(a);
  if (blockIdx.x == 0 && threadIdx.x < 16) {
    float s = 0.f;
    for (int k = 0; k < 64; k++) s += kb[threadIdx.x * 64 + k] * q[threadIdx.x * 64 + k];
    qb[threadIdx.x] = s;
  }
}

// ---------------- K2: fused MFMA logits + chunk softmax + weighted sum ----------------
// 512 blocks (32 b x 16 chunks of 64 rows), 512 thr (8 waves).
// LDS: qkt (B-frags fp16) 32 KB read-only after staging + et2 4.3 KB.
// Wave wid = (khalf<<2)|wtile: rows [wtile*16,+16), K-half khalf*512.
__global__ __launch_bounds__(512, 4) void k_fused(const float* __restrict__ x,
                                                  const __half* __restrict__ qkb,
                                                  const float* __restrict__ qb,
                                                  float* __restrict__ mch,
                                                  float* __restrict__ lch,
                                                  __half* __restrict__ wph) {
  __shared__ __half qkt[16384];    // 32 KB B-fragments
  __shared__ float et2[64 * 17 + 4];
  const int tid = threadIdx.x;
  const int lane = tid & 63;
  const int wid = tid >> 6;          // 0..7
  const int blk = blockIdx.x;        // b*16 + ch
  const int srow0 = blk * 64;        // global row base

  // stage qkb -> qkt (identity copy, 2048 uint4)
#pragma unroll
  for (int it = 0; it < 4; ++it) {
    const int g = it * 512 + tid;
    ((uint4*)qkt)[g] = ((const uint4*)qkb)[g];
  }
  __syncthreads();

  // ---- Phase A: logits via MFMA ----
  {
    const int wtile = wid & 3;       // row tile 0..3
    const int khalf = wid >> 2;      // K half 0..1
    const int r16 = lane & 15;       // A row within tile / D col (n)
    const int khi = lane >> 4;       // 0..3
    const float* xg = x + (size_t)(srow0 + wtile * 16 + r16) * 1024
                        + khalf * 512 + khi * 8;
    const __half* qbase = qkt + (khalf * 16) * 512 + lane * 8;

    f32x4 dacc = {0.f, 0.f, 0.f, 0.f};
    float4 pa0 = *(const float4*)(xg);
    float4 pa1 = *(const float4*)(xg + 4);
    float4 pb0, pb1;

#pragma unroll 1
    for (int kbs = 0; kbs < 16; kbs += 2) {
      pb0 = *(const float4*)(xg + (kbs + 1) * 32);
      pb1 = *(const float4*)(xg + (kbs + 1) * 32 + 4);
      {
        f16x8 af;
        af[0] = (_Float16)pa0.x; af[1] = (_Float16)pa0.y;
        af[2] = (_Float16)pa0.z; af[3] = (_Float16)pa0.w;
        af[4] = (_Float16)pa1.x; af[5] = (_Float16)pa1.y;
        af[6] = (_Float16)pa1.z; af[7] = (_Float16)pa1.w;
        const f16x8 bf = *(const f16x8*)(qbase + kbs * 512);
        dacc = __builtin_amdgcn_mfma_f32_16x16x32_f16(af, bf, dacc, 0, 0, 0);
      }
      if (kbs + 2 < 16) {
        pa0 = *(const float4*)(xg + (kbs + 2) * 32);
        pa1 = *(const float4*)(xg + (kbs + 2) * 32 + 4);
      }
      {
        f16x8 af;
        af[0] = (_Float16)pb0.x; af[1] = (_Float16)pb0.y;
        af[2] = (_Float16)pb0.z; af[3] = (_Float16)pb0.w;
        af[4] = (_Float16)pb1.x; af[5] = (_Float16)pb1.y;
        af[6] = (_Float16)pb1.z; af[7] = (_Float16)pb1.w;
        const f16x8 bf = *(const f16x8*)(qbase + (kbs + 1) * 512);
        dacc = __builtin_amdgcn_mfma_f32_16x16x32_f16(af, bf, dacc, 0, 0, 0);
      }
    }

    // D layout: row = khi*4+reg (s within tile), col = r16 (n)  [m89-verified]
    const float qbv = qb[r16];
    if (khalf == 0) {
#pragma unroll
      for (int reg = 0; reg < 4; ++reg)
        et2[(wtile * 16 + khi * 4 + reg) * 17 + r16] = dacc[reg] + qbv;
    }
    __syncthreads();
    if (khalf == 1) {
#pragma unroll
      for (int reg = 0; reg < 4; ++reg)
        et2[(wtile * 16 + khi * 4 + reg) * 17 + r16] += dacc[reg];
    }
    __syncthreads();
  }

  // ---- Phase B: chunk softmax per n (wave handles n = wid, wid+8) ----
#pragma unroll
  for (int t = 0; t < 2; ++t) {
    const int nn = wid + t * 8;
    const float v = et2[lane * 17 + nn];
    float m = v;
#pragma unroll
    for (int d = 1; d < 64; d <<= 1) m = fmaxf(m, __shfl_xor(m, d));
    const float e = __expf(v - m);
    float s = e;
#pragma unroll
    for (int d = 1; d < 64; d <<= 1) s += __shfl_xor(s, d);
    if (lane == 0) {
      mch[blk * 16 + nn] = m;
      lch[blk * 16 + nn] = s;
    }
    et2[lane * 17 + nn] = e;   // in-place, same thread -> no race
  }
  __syncthreads();

  // ---- Phase C: wp[blk][n][c] = sum_s e[s][n]*x[s][c], c = {2*tid, 2*tid+1} ----
  {
    const int c0 = tid * 2;
    float acc0[16], acc1[16];
#pragma unroll
    for (int n = 0; n < 16; ++n) { acc0[n] = 0.f; acc1[n] = 0.f; }
    const float* xp = x + (size_t)srow0 * 1024 + c0;

    // rolling distance-1 pipeline with named buffers (R7/R10/R12 discipline)
    float  ea = et2[(lane >> 4) * 17 + (lane & 15)];
    float2 xca[4];
#pragma unroll
    for (int ss = 0; ss < 4; ++ss) xca[ss] = *(const float2*)(xp + (size_t)ss * 1024);

#pragma unroll 1
    for (int sg = 0; sg < 16; ++sg) {
      float  eb = 0.f;
      float2 xcb[4];
      if (sg < 15) {
        const int s0n = (sg + 1) * 4;
        eb = et2[(s0n + (lane >> 4)) * 17 + (lane & 15)];
#pragma unroll
        for (int ss = 0; ss < 4; ++ss)
          xcb[ss] = *(const float2*)(xp + (size_t)(s0n + ss) * 1024);
      }
#pragma unroll
      for (int ss = 0; ss < 4; ++ss) {
#pragma unroll
        for (int n = 0; n < 16; ++n) {
          const float ev = rlane(ea, ss * 16 + n);  // lane ss*16+n holds e[sg*4+ss][n]
          acc0[n] += ev * xca[ss].x;
          acc1[n] += ev * xca[ss].y;
        }
      }
      ea = eb;
#pragma unroll
      for (int ss = 0; ss < 4; ++ss) xca[ss] = xcb[ss];
    }

    __half* wpp = wph + (size_t)blk * 16384;
#pragma unroll
    for (int n = 0; n < 16; ++n) {
      __half2 h = __floats2half2_rn(acc0[n], acc1[n]);
      *(__half2*)(wpp + n * 1024 + c0) = h;
    }
  }
}

// ---------------- K3: out = (sum_ch fac*wp . vk)/lg + vb ----------------
__global__ __launch_bounds__(256) void k_out(const __half* __restrict__ wph,
                                             const float* __restrict__ vk,
                                             const float* __restrict__ vb,
                                             const float* __restrict__ mch,
                                             const float* __restrict__ lch,
                                             float* __restrict__ out) {
  const int bi = blockIdx.x;  // b*16+n, 512 blocks
  const int b = bi >> 4, n = bi & 15;
  const int tid = threadIdx.x;
  __shared__ float wrow[1024];
  __shared__ float red[4][64];

  float m16[16], l16[16];
#pragma unroll
  for (int ch = 0; ch < 16; ++ch) {
    m16[ch] = mch[(b * 16 + ch) * 16 + n];
    l16[ch] = lch[(b * 16 + ch) * 16 + n];
  }
  float mg = m16[0];
#pragma unroll
  for (int ch = 1; ch < 16; ++ch) mg = fmaxf(mg, m16[ch]);
  float fac[16], lg = 0.f;
#pragma unroll
  for (int ch = 0; ch < 16; ++ch) { fac[ch] = __expf(m16[ch] - mg); lg += fac[ch] * l16[ch]; }

  float4 a4 = {0.f, 0.f, 0.f, 0.f};
#pragma unroll
  for (int ch = 0; ch < 16; ch++) {
    const __half2* p = (const __half2*)(wph + ((size_t)(b * 16 + ch) * 16 + n) * 1024 + tid * 4);
    const float2 f01 = __half22float2(p[0]);
    const float2 f23 = __half22float2(p[1]);
    a4.x += fac[ch] * f01.x; a4.y += fac[ch] * f01.y;
    a4.z += fac[ch] * f23.x; a4.w += fac[ch] * f23.y;
  }
  *(float4*)&wrow[tid * 4] = a4;
  __syncthreads();

  const int v = tid & 63, cq = tid >> 6;
  float a = 0.f;
  const float* vkc = vk + n * 64 + v;
  for (int ci = 0; ci < 256; ci++) {
    const int c = cq * 256 + ci;
    a += wrow[c] * vkc[(size_t)c * 1024];
  }
  red[cq][v] = a;
  __syncthreads();
  if (tid < 64) {
    const float o = (red[0][tid] + red[1][tid] + red[2][tid] + red[3][tid]) / lg
                    + vb[n * 64 + tid];
    out[(size_t)b * 1024 + n * 64 + tid] = o;
  }
}

extern "C" void kernel_launch(void* const* d_in, const int* in_sizes, int n_in,
                              void* d_out, int out_size, void* d_ws, size_t ws_size,
                              hipStream_t stream) {
  const float* x  = (const float*)d_in[0];  // key_value [32,32,32,1024]
  const float* q  = (const float*)d_in[1];  // query [1,1,16,64]
  const float* kk = (const float*)d_in[2];  // k_kernel [1024,1024]
  const float* kb = (const float*)d_in[3];  // k_bias [1024]
  const float* vk = (const float*)d_in[4];  // v_kernel [1024,1024]
  const float* vb = (const float*)d_in[5];  // v_bias [1024]
  float* out = (float*)d_out;               // [32,16,64] fp32

  float*  f   = (float*)d_ws;
  __half* qkb = (__half*)f;            // 16384 halves = 32 KB (B-fragment layout)
  float*  qb  = f + 8192;              // 16
  float*  mch = f + 8208;              // 8192  [512 blk][16 n]
  float*  lch = f + 16400;             // 8192
  __half* wph = (__half*)(f + 24592);  // 8388608 halves = 16 MB

  hipLaunchKernelGGL(k_qk,    dim3(64),  dim3(256), 0, stream, kk, q, kb, qkb, qb);
  hipLaunchKernelGGL(k_fused, dim3(512), dim3(512), 0, stream, x, qkb, qb, mch, lch, wph);
  hipLaunchKernelGGL(k_out,   dim3(512), dim3(256), 0, stream, wph, vk, vb, mch, lch, out);
}